// Round 7
// baseline (694.577 us; speedup 1.0000x reference)
//
#include <hip/hip_runtime.h>

#define NN 100000
#define NE 1600000
#define EPSV 1e-5f
#define SCHUNK 1024
#define SNB ((NN + SCHUNK - 1) / SCHUNK)  // 98
#define BNODES 200
#define NBUK (NN / BNODES)  // 500
#define EPB 4096
#define NMB ((NE + EPB - 1) / EPB)  // 391
#define MATP 400

typedef unsigned short u16;
typedef __attribute__((ext_vector_type(8))) short bf16x8;
typedef __attribute__((ext_vector_type(4))) float f32x4;

#define MFMA16(a, b, c) __builtin_amdgcn_mfma_f32_16x16x32_bf16(a, b, c, 0, 0, 0)

__device__ __forceinline__ u16 f2bf(float f) {
  unsigned u = __float_as_uint(f);
  unsigned r = u + 0x7fffu + ((u >> 16) & 1u);
  return (u16)(r >> 16);
}
__device__ __forceinline__ float b2f(u16 h) { return __uint_as_float(((unsigned)h) << 16); }
__device__ __forceinline__ float bflo(unsigned u) { return __uint_as_float(u << 16); }
__device__ __forceinline__ float bfhi(unsigned u) { return __uint_as_float(u & 0xffff0000u); }

// ---------- CSR build ----------
__global__ __launch_bounds__(256) void hist_k(const int* __restrict__ dst, int* __restrict__ cnt) {
  int e = blockIdx.x * 256 + threadIdx.x;
  if (e < NE) atomicAdd(&cnt[dst[e]], 1);
}

__global__ __launch_bounds__(256) void scan1_k(const int* __restrict__ cnt, int* __restrict__ partial) {
  __shared__ int ws[4];
  const int t = threadIdx.x;
  const int base = blockIdx.x * SCHUNK;
  int s = 0;
  for (int i = t; i < SCHUNK; i += 256) {
    int idx = base + i;
    s += (idx < NN) ? cnt[idx] : 0;
  }
#pragma unroll
  for (int m = 1; m < 64; m <<= 1) s += __shfl_xor(s, m, 64);
  if ((t & 63) == 0) ws[t >> 6] = s;
  __syncthreads();
  if (t == 0) partial[blockIdx.x] = ws[0] + ws[1] + ws[2] + ws[3];
}

__global__ __launch_bounds__(128) void scan2_k(int* __restrict__ partial) {
  __shared__ int sm[128];
  const int t = threadIdx.x;
  int v = (t < SNB) ? partial[t] : 0;
  sm[t] = v;
  __syncthreads();
  for (int off = 1; off < 128; off <<= 1) {
    int u = (t >= off) ? sm[t - off] : 0;
    __syncthreads();
    sm[t] += u;
    __syncthreads();
  }
  if (t < SNB) partial[t] = sm[t] - v;
}

__global__ __launch_bounds__(256) void scan3_k(const int* __restrict__ cnt, const int* __restrict__ partial,
                                               int* __restrict__ row_ptr) {
  __shared__ int sm[256];
  const int t = threadIdx.x;
  const int base = blockIdx.x * SCHUNK + t * 4;
  int c[4];
  int s = 0;
#pragma unroll
  for (int i = 0; i < 4; ++i) {
    int idx = base + i;
    c[i] = (idx < NN) ? cnt[idx] : 0;
    s += c[i];
  }
  sm[t] = s;
  __syncthreads();
  for (int off = 1; off < 256; off <<= 1) {
    int u = (t >= off) ? sm[t - off] : 0;
    __syncthreads();
    sm[t] += u;
    __syncthreads();
  }
  int run = partial[blockIdx.x] + sm[t] - s;
#pragma unroll
  for (int i = 0; i < 4; ++i) {
    int idx = base + i;
    if (idx < NN) {
      row_ptr[idx] = run;
      run += c[i];
    }
  }
  if (blockIdx.x == 0 && t == 0) row_ptr[NN] = NE;
}

// ---------- block multisplit into 500 buckets (no global atomics) ----------
__global__ __launch_bounds__(256) void mcount_k(const int* __restrict__ dst, int* __restrict__ mat) {
  __shared__ int cnt[NBUK];
  const int t = threadIdx.x;
  const int blk = blockIdx.x;
  for (int i = t; i < NBUK; i += 256) cnt[i] = 0;
  __syncthreads();
  const int e0 = blk * EPB;
  const int e1 = min(e0 + EPB, NE);
  for (int e = e0 + t; e < e1; e += 256) atomicAdd(&cnt[dst[e] / BNODES], 1);
  __syncthreads();
  for (int i = t; i < NBUK; i += 256) mat[i * MATP + blk] = cnt[i];
}

__global__ __launch_bounds__(256) void mscan_k(int* __restrict__ mat, const int* __restrict__ row_ptr) {
  __shared__ int sm[512];
  const int b = blockIdx.x;
  const int t = threadIdx.x;
  sm[t] = (t < NMB) ? mat[b * MATP + t] : 0;
  sm[t + 256] = (t + 256 < NMB) ? mat[b * MATP + t + 256] : 0;
  __syncthreads();
  for (int off = 1; off < 512; off <<= 1) {
    int a0 = (t >= off) ? sm[t - off] : 0;
    int a1 = (t + 256 >= off) ? sm[t + 256 - off] : 0;
    __syncthreads();
    sm[t] += a0;
    sm[t + 256] += a1;
    __syncthreads();
  }
  const int base = row_ptr[b * BNODES];
  if (t < NMB) mat[b * MATP + t] = base + ((t == 0) ? 0 : sm[t - 1]);
  if (t + 256 < NMB) mat[b * MATP + t + 256] = base + sm[t + 255];
}

__global__ __launch_bounds__(256) void mscatter_k(const int* __restrict__ src, const int* __restrict__ dst,
                                                  const int* __restrict__ mat, int2* __restrict__ staging) {
  __shared__ int off[NBUK];
  const int t = threadIdx.x;
  const int blk = blockIdx.x;
  for (int i = t; i < NBUK; i += 256) off[i] = mat[i * MATP + blk];
  __syncthreads();
  const int e0 = blk * EPB;
  const int e1 = min(e0 + EPB, NE);
  for (int e = e0 + t; e < e1; e += 256) {
    int d = dst[e];
    int s = src[e];
    int b = d / BNODES;
    int p = atomicAdd(&off[b], 1);
    staging[p] = make_int2(s, d - b * BNODES);
  }
}

__global__ __launch_bounds__(256) void place2_k(const int* __restrict__ row_ptr,
                                                const int2* __restrict__ staging, int* __restrict__ ssorted) {
  __shared__ int cur[BNODES];
  const int b = blockIdx.x;
  const int t = threadIdx.x;
  const int nbase = b * BNODES;
  if (t < BNODES) cur[t] = row_ptr[nbase + t];
  __syncthreads();
  const int lo = row_ptr[nbase];
  const int hi = row_ptr[nbase + BNODES];
  for (int i = lo + t; i < hi; i += 256) {
    int2 v = staging[i];
    int p = atomicAdd(&cur[v.y], 1);
    ssorted[p] = v.x;
  }
}

// ---------- fp32 -> bf16 hi/lo split (layer-0 input only) ----------
__global__ __launch_bounds__(256) void split_k(const float* __restrict__ h,
                                               u16* __restrict__ xh, u16* __restrict__ xl) {
  int i = blockIdx.x * 256 + threadIdx.x;
  float4 v = reinterpret_cast<const float4*>(h)[i];
  ushort4 hv, lv;
  hv.x = f2bf(v.x); lv.x = f2bf(v.x - b2f(hv.x));
  hv.y = f2bf(v.y); lv.y = f2bf(v.y - b2f(hv.y));
  hv.z = f2bf(v.z); lv.z = f2bf(v.z - b2f(hv.z));
  hv.w = f2bf(v.w); lv.w = f2bf(v.w - b2f(hv.w));
  reinterpret_cast<ushort4*>(xh)[i] = hv;
  reinterpret_cast<ushort4*>(xl)[i] = lv;
}

// ---------- weight transpose + split: W[128][J] -> Wt[Jpad][128] hi/lo ----------
__global__ __launch_bounds__(256) void wprep_k(const float* __restrict__ W, int J, int Jpad,
                                               u16* __restrict__ wh, u16* __restrict__ wl) {
  int idx = blockIdx.x * 256 + threadIdx.x;
  if (idx >= Jpad * 128) return;
  int j = idx >> 7, k = idx & 127;
  float v = (j < J) ? W[k * J + j] : 0.f;
  u16 hv = f2bf(v);
  wh[idx] = hv;
  wl[idx] = f2bf(v - b2f(hv));
}

// ---------- mean aggregation: one wave64 per node, plain bf16 out ----------
__global__ __launch_bounds__(256) void agg_k(const u16* __restrict__ x, const int* __restrict__ row_ptr,
                                             const int* __restrict__ ss, u16* __restrict__ agg) {
  int gid = blockIdx.x * 256 + threadIdx.x;
  int node = gid >> 6;
  int lane = threadIdx.x & 63;
  if (node >= NN) return;
  int s0 = row_ptr[node], s1 = row_ptr[node + 1];
  float ax = 0.f, ay = 0.f;
  int e = s0;
  for (; e + 2 <= s1; e += 2) {
    int sA = ss[e], sB = ss[e + 1];
    unsigned a = *reinterpret_cast<const unsigned*>(x + (size_t)sA * 128 + lane * 2);
    unsigned b = *reinterpret_cast<const unsigned*>(x + (size_t)sB * 128 + lane * 2);
    ax += bflo(a) + bflo(b);
    ay += bfhi(a) + bfhi(b);
  }
  if (e < s1) {
    unsigned a = *reinterpret_cast<const unsigned*>(x + (size_t)ss[e] * 128 + lane * 2);
    ax += bflo(a);
    ay += bfhi(a);
  }
  float sc = (s1 > s0) ? 1.0f / (float)(s1 - s0) : 0.0f;
  *reinterpret_cast<unsigned*>(agg + (size_t)node * 128 + lane * 2) =
      (unsigned)f2bf(ax * sc) | ((unsigned)f2bf(ay * sc) << 16);
}

// ---------- GEMM passes, 16 rows/wave ----------
// acc += A@B (+ A2@B if HAS2), K=128, NT col-tiles of 16
template <int NT, int HAS2>
__device__ __forceinline__ void gpass16(const u16* __restrict__ A, const u16* __restrict__ A2,
                                        const u16* __restrict__ B, int row, int lr, int lg,
                                        f32x4 (&acc)[NT]) {
#pragma unroll
  for (int ks = 0; ks < 4; ++ks) {
    const int ko = ks * 32 + lg * 8;
    bf16x8 a0 = *reinterpret_cast<const bf16x8*>(A + (size_t)row * 128 + ko);
    bf16x8 c0 = a0;
    if (HAS2) c0 = *reinterpret_cast<const bf16x8*>(A2 + (size_t)row * 128 + ko);
#pragma unroll
    for (int t = 0; t < NT; ++t) {
      bf16x8 b = *reinterpret_cast<const bf16x8*>(B + (size_t)(t * 16 + lr) * 128 + ko);
      acc[t] = MFMA16(a0, b, acc[t]);
      if (HAS2) acc[t] = MFMA16(c0, b, acc[t]);
    }
  }
}
// acc += A@Bh + A@Bl (one A-load, two weight streams)
template <int NT>
__device__ __forceinline__ void gpassW(const u16* __restrict__ A, const u16* __restrict__ Bh,
                                       const u16* __restrict__ Bl, int row, int lr, int lg,
                                       f32x4 (&acc)[NT]) {
#pragma unroll
  for (int ks = 0; ks < 4; ++ks) {
    const int ko = ks * 32 + lg * 8;
    bf16x8 a0 = *reinterpret_cast<const bf16x8*>(A + (size_t)row * 128 + ko);
#pragma unroll
    for (int t = 0; t < NT; ++t) {
      bf16x8 bh = *reinterpret_cast<const bf16x8*>(Bh + (size_t)(t * 16 + lr) * 128 + ko);
      bf16x8 bl = *reinterpret_cast<const bf16x8*>(Bl + (size_t)(t * 16 + lr) * 128 + ko);
      acc[t] = MFMA16(a0, bh, acc[t]);
      acc[t] = MFMA16(a0, bl, acc[t]);
    }
  }
}

// ---------- fused SAGE layer: GEMM + bias + LN + ReLU; 16 rows/wave, 64 rows/block ----------
// XSPLIT=1: x has hi+lo (layer 0). XSPLIT=0: x plain bf16.
template <int XSPLIT>
__global__ __launch_bounds__(256) void gemm_ln_k(
    const u16* __restrict__ xh, const u16* __restrict__ xl, const u16* __restrict__ ag,
    const u16* __restrict__ wsh, const u16* __restrict__ wsl,
    const u16* __restrict__ wnh, const u16* __restrict__ wnl,
    const float* __restrict__ bias, const float* __restrict__ gamma, const float* __restrict__ beta,
    u16* __restrict__ yh) {
  const int lane = threadIdx.x & 63;
  const int wv = threadIdx.x >> 6;
  const int r0 = blockIdx.x * 64 + wv * 16;
  if (r0 >= NN) return;
  const int lr = lane & 15, lg = lane >> 4;
  const int row = r0 + lr;

  f32x4 acc[8];
#pragma unroll
  for (int t = 0; t < 8; ++t) acc[t] = f32x4{0.f, 0.f, 0.f, 0.f};

  if (XSPLIT) {
    gpass16<8, 1>(xh, xl, wsh, row, lr, lg, acc);  // (x_hi + x_lo) @ Ws_hi
    gpass16<8, 0>(xh, xh, wsl, row, lr, lg, acc);  // x_hi @ Ws_lo
  } else {
    gpassW<8>(xh, wsh, wsl, row, lr, lg, acc);     // x @ (Ws_hi + Ws_lo)
  }
  gpassW<8>(ag, wnh, wnl, row, lr, lg, acc);       // agg @ (Wn_hi + Wn_lo)

  float bcol[8], gcol[8], ecol[8];
#pragma unroll
  for (int t = 0; t < 8; ++t) {
    int c = t * 16 + lr;
    bcol[t] = bias[c];
    gcol[t] = gamma[c];
    ecol[t] = beta[c];
  }

  float v[8][4];
#pragma unroll
  for (int t = 0; t < 8; ++t)
#pragma unroll
    for (int e = 0; e < 4; ++e) v[t][e] = acc[t][e] + bcol[t];
  float mu[4], inv[4];
#pragma unroll
  for (int e = 0; e < 4; ++e) {
    float s = 0.f;
#pragma unroll
    for (int t = 0; t < 8; ++t) s += v[t][e];
    s += __shfl_xor(s, 1, 64);
    s += __shfl_xor(s, 2, 64);
    s += __shfl_xor(s, 4, 64);
    s += __shfl_xor(s, 8, 64);
    mu[e] = s * 0.0078125f;
  }
#pragma unroll
  for (int e = 0; e < 4; ++e) {
    float q = 0.f;
#pragma unroll
    for (int t = 0; t < 8; ++t) {
      float d = v[t][e] - mu[e];
      q += d * d;
    }
    q += __shfl_xor(q, 1, 64);
    q += __shfl_xor(q, 2, 64);
    q += __shfl_xor(q, 4, 64);
    q += __shfl_xor(q, 8, 64);
    inv[e] = rsqrtf(q * 0.0078125f + EPSV);
  }
#pragma unroll
  for (int t = 0; t < 8; ++t)
#pragma unroll
    for (int e = 0; e < 4; ++e) {
      float o = fmaxf((v[t][e] - mu[e]) * inv[e] * gcol[t] + ecol[t], 0.f);
      yh[(size_t)(r0 + lg * 4 + e) * 128 + t * 16 + lr] = f2bf(o);
    }
}

// ---------- final layer: [N,128]@[128,47] x2 + bias -> fp32 out; 16 rows/wave ----------
__global__ __launch_bounds__(256) void gemm_out_k(
    const u16* __restrict__ x, const u16* __restrict__ ag,
    const u16* __restrict__ wsh, const u16* __restrict__ wsl,
    const u16* __restrict__ wnh, const u16* __restrict__ wnl,
    const float* __restrict__ bias, float* __restrict__ out) {
  const int lane = threadIdx.x & 63;
  const int wv = threadIdx.x >> 6;
  const int r0 = blockIdx.x * 64 + wv * 16;
  if (r0 >= NN) return;
  const int lr = lane & 15, lg = lane >> 4;
  const int row = r0 + lr;

  f32x4 acc[3];
#pragma unroll
  for (int t = 0; t < 3; ++t) acc[t] = f32x4{0.f, 0.f, 0.f, 0.f};

  gpassW<3>(x, wsh, wsl, row, lr, lg, acc);
  gpassW<3>(ag, wnh, wnl, row, lr, lg, acc);

  float bcol[3];
#pragma unroll
  for (int t = 0; t < 3; ++t) {
    int c = t * 16 + lr;
    bcol[t] = (c < 47) ? bias[c] : 0.f;
  }
#pragma unroll
  for (int t = 0; t < 3; ++t) {
    int col = t * 16 + lr;
    if (col < 47) {
#pragma unroll
      for (int e = 0; e < 4; ++e) {
        int r = r0 + lg * 4 + e;
        out[(size_t)r * 47 + col] = acc[t][e] + bcol[t];
      }
    }
  }
}

extern "C" void kernel_launch(void* const* d_in, const int* in_sizes, int n_in,
                              void* d_out, int out_size, void* d_ws, size_t ws_size,
                              hipStream_t stream) {
  const float* h = (const float*)d_in[0];
  const int* src = (const int*)d_in[1];
  const int* dst = (const int*)d_in[2];
  const float* Ws0 = (const float*)d_in[3];
  const float* Wn0 = (const float*)d_in[4];
  const float* b0 = (const float*)d_in[5];
  const float* g0 = (const float*)d_in[6];
  const float* be0 = (const float*)d_in[7];
  const float* Ws1 = (const float*)d_in[8];
  const float* Wn1 = (const float*)d_in[9];
  const float* b1 = (const float*)d_in[10];
  const float* g1 = (const float*)d_in[11];
  const float* be1 = (const float*)d_in[12];
  const float* Ws2 = (const float*)d_in[13];
  const float* Wn2 = (const float*)d_in[14];
  const float* b2 = (const float*)d_in[15];
  float* out = (float*)d_out;

  // workspace layout (all 16B aligned)
  u16* x_hi = (u16*)d_ws;                       // N*128
  u16* x_lo = x_hi + (size_t)NN * 128;          // N*128 (layer-0 input lo)
  u16* aggb = x_lo + (size_t)NN * 128;          // N*128 (plain bf16 agg)
  u16* spare = aggb + (size_t)NN * 128;         // N*128 spare (CSR temps)
  int* row_ptr = (int*)(spare + (size_t)NN * 128);   // N+1 (+pad)
  int* ssorted = row_ptr + (NN + 4);            // E
  int* partial = ssorted + NE;                  // SNB (+pad)
  u16* wbuf = (u16*)(partial + 128);
  u16 *w0sh = wbuf, *w0sl = wbuf + 16384, *w0nh = wbuf + 32768, *w0nl = wbuf + 49152;
  u16 *w1sh = wbuf + 65536, *w1sl = wbuf + 81920, *w1nh = wbuf + 98304, *w1nl = wbuf + 114688;
  u16 *w2sh = wbuf + 131072, *w2sl = wbuf + 137216, *w2nh = wbuf + 143360, *w2nl = wbuf + 149504;
  // CSR temps live in aggb/spare before first agg_k write:
  int* cnt = (int*)aggb;                   // N counts (hist)
  int* mat = cnt + NN;                     // NBUK*MATP offsets (800 KB)
  int2* staging = (int2*)spare;            // E packed (src, dst_local) (12.8 MB)

  // CSR build: hist -> hierarchical scan -> atomic-free multisplit -> bucket scatter
  hipMemsetAsync(cnt, 0, NN * sizeof(int), stream);
  hist_k<<<(NE + 255) / 256, 256, 0, stream>>>(dst, cnt);
  scan1_k<<<SNB, 256, 0, stream>>>(cnt, partial);
  scan2_k<<<1, 128, 0, stream>>>(partial);
  scan3_k<<<SNB, 256, 0, stream>>>(cnt, partial, row_ptr);
  mcount_k<<<NMB, 256, 0, stream>>>(dst, mat);
  mscan_k<<<NBUK, 256, 0, stream>>>(mat, row_ptr);
  mscatter_k<<<NMB, 256, 0, stream>>>(src, dst, mat, staging);
  place2_k<<<NBUK, 256, 0, stream>>>(row_ptr, staging, ssorted);

  // feature split + weight prep
  split_k<<<(NN * 128 / 4 + 255) / 256, 256, 0, stream>>>(h, x_hi, x_lo);
  wprep_k<<<64, 256, 0, stream>>>(Ws0, 128, 128, w0sh, w0sl);
  wprep_k<<<64, 256, 0, stream>>>(Wn0, 128, 128, w0nh, w0nl);
  wprep_k<<<64, 256, 0, stream>>>(Ws1, 128, 128, w1sh, w1sl);
  wprep_k<<<64, 256, 0, stream>>>(Wn1, 128, 128, w1nh, w1nl);
  wprep_k<<<24, 256, 0, stream>>>(Ws2, 47, 48, w2sh, w2sl);
  wprep_k<<<24, 256, 0, stream>>>(Wn2, 47, 48, w2nh, w2nl);

  const int AGG_GRID = (NN * 64 + 255) / 256;
  const int GEMM_GRID = (NN + 63) / 64;

  // layer 0 (x split hi+lo)
  agg_k<<<AGG_GRID, 256, 0, stream>>>(x_hi, row_ptr, ssorted, aggb);
  gemm_ln_k<1><<<GEMM_GRID, 256, 0, stream>>>(x_hi, x_lo, aggb,
                                              w0sh, w0sl, w0nh, w0nl, b0, g0, be0, x_hi);
  // layer 1 (plain bf16 activations, in-place)
  agg_k<<<AGG_GRID, 256, 0, stream>>>(x_hi, row_ptr, ssorted, aggb);
  gemm_ln_k<0><<<GEMM_GRID, 256, 0, stream>>>(x_hi, nullptr, aggb,
                                              w1sh, w1sl, w1nh, w1nl, b1, g1, be1, x_hi);
  // layer 2
  agg_k<<<AGG_GRID, 256, 0, stream>>>(x_hi, row_ptr, ssorted, aggb);
  gemm_out_k<<<GEMM_GRID, 256, 0, stream>>>(x_hi, aggb,
                                            w2sh, w2sl, w2nh, w2nl, b2, out);
}

// Round 8
// 525.744 us; speedup vs baseline: 1.3211x; 1.3211x over previous
//
#include <hip/hip_runtime.h>

#define NN 100000
#define NE 1600000
#define EPSV 1e-5f
#define SCHUNK 1024
#define SNB ((NN + SCHUNK - 1) / SCHUNK)  // 98
#define BNODES 200
#define NBUK (NN / BNODES)  // 500
#define EPB 4096
#define NMB ((NE + EPB - 1) / EPB)  // 391
#define MATP 400

typedef unsigned short u16;
typedef __attribute__((ext_vector_type(8))) short bf16x8;
typedef __attribute__((ext_vector_type(4))) float f32x4;

#define MFMA16(a, b, c) __builtin_amdgcn_mfma_f32_16x16x32_bf16(a, b, c, 0, 0, 0)

__device__ __forceinline__ u16 f2bf(float f) {
  unsigned u = __float_as_uint(f);
  unsigned r = u + 0x7fffu + ((u >> 16) & 1u);
  return (u16)(r >> 16);
}
__device__ __forceinline__ float b2f(u16 h) { return __uint_as_float(((unsigned)h) << 16); }
__device__ __forceinline__ float bflo(unsigned u) { return __uint_as_float(u << 16); }
__device__ __forceinline__ float bfhi(unsigned u) { return __uint_as_float(u & 0xffff0000u); }

// ---------- CSR build ----------
__global__ __launch_bounds__(256) void hist_k(const int* __restrict__ dst, int* __restrict__ cnt) {
  int e = blockIdx.x * 256 + threadIdx.x;
  if (e < NE) atomicAdd(&cnt[dst[e]], 1);
}

__global__ __launch_bounds__(256) void scan1_k(const int* __restrict__ cnt, int* __restrict__ partial) {
  __shared__ int ws[4];
  const int t = threadIdx.x;
  const int base = blockIdx.x * SCHUNK;
  int s = 0;
  for (int i = t; i < SCHUNK; i += 256) {
    int idx = base + i;
    s += (idx < NN) ? cnt[idx] : 0;
  }
#pragma unroll
  for (int m = 1; m < 64; m <<= 1) s += __shfl_xor(s, m, 64);
  if ((t & 63) == 0) ws[t >> 6] = s;
  __syncthreads();
  if (t == 0) partial[blockIdx.x] = ws[0] + ws[1] + ws[2] + ws[3];
}

__global__ __launch_bounds__(128) void scan2_k(int* __restrict__ partial) {
  __shared__ int sm[128];
  const int t = threadIdx.x;
  int v = (t < SNB) ? partial[t] : 0;
  sm[t] = v;
  __syncthreads();
  for (int off = 1; off < 128; off <<= 1) {
    int u = (t >= off) ? sm[t - off] : 0;
    __syncthreads();
    sm[t] += u;
    __syncthreads();
  }
  if (t < SNB) partial[t] = sm[t] - v;
}

__global__ __launch_bounds__(256) void scan3_k(const int* __restrict__ cnt, const int* __restrict__ partial,
                                               int* __restrict__ row_ptr) {
  __shared__ int sm[256];
  const int t = threadIdx.x;
  const int base = blockIdx.x * SCHUNK + t * 4;
  int c[4];
  int s = 0;
#pragma unroll
  for (int i = 0; i < 4; ++i) {
    int idx = base + i;
    c[i] = (idx < NN) ? cnt[idx] : 0;
    s += c[i];
  }
  sm[t] = s;
  __syncthreads();
  for (int off = 1; off < 256; off <<= 1) {
    int u = (t >= off) ? sm[t - off] : 0;
    __syncthreads();
    sm[t] += u;
    __syncthreads();
  }
  int run = partial[blockIdx.x] + sm[t] - s;
#pragma unroll
  for (int i = 0; i < 4; ++i) {
    int idx = base + i;
    if (idx < NN) {
      row_ptr[idx] = run;
      run += c[i];
    }
  }
  if (blockIdx.x == 0 && t == 0) row_ptr[NN] = NE;
}

// ---------- block multisplit into 500 buckets (no global atomics) ----------
__global__ __launch_bounds__(256) void mcount_k(const int* __restrict__ dst, int* __restrict__ mat) {
  __shared__ int cnt[NBUK];
  const int t = threadIdx.x;
  const int blk = blockIdx.x;
  for (int i = t; i < NBUK; i += 256) cnt[i] = 0;
  __syncthreads();
  const int e0 = blk * EPB;
  const int e1 = min(e0 + EPB, NE);
  for (int e = e0 + t; e < e1; e += 256) atomicAdd(&cnt[dst[e] / BNODES], 1);
  __syncthreads();
  for (int i = t; i < NBUK; i += 256) mat[i * MATP + blk] = cnt[i];
}

__global__ __launch_bounds__(256) void mscan_k(int* __restrict__ mat, const int* __restrict__ row_ptr) {
  __shared__ int sm[512];
  const int b = blockIdx.x;
  const int t = threadIdx.x;
  sm[t] = (t < NMB) ? mat[b * MATP + t] : 0;
  sm[t + 256] = (t + 256 < NMB) ? mat[b * MATP + t + 256] : 0;
  __syncthreads();
  for (int off = 1; off < 512; off <<= 1) {
    int a0 = (t >= off) ? sm[t - off] : 0;
    int a1 = (t + 256 >= off) ? sm[t + 256 - off] : 0;
    __syncthreads();
    sm[t] += a0;
    sm[t + 256] += a1;
    __syncthreads();
  }
  const int base = row_ptr[b * BNODES];
  if (t < NMB) mat[b * MATP + t] = base + ((t == 0) ? 0 : sm[t - 1]);
  if (t + 256 < NMB) mat[b * MATP + t + 256] = base + sm[t + 255];
}

__global__ __launch_bounds__(256) void mscatter_k(const int* __restrict__ src, const int* __restrict__ dst,
                                                  const int* __restrict__ mat, int2* __restrict__ staging) {
  __shared__ int off[NBUK];
  const int t = threadIdx.x;
  const int blk = blockIdx.x;
  for (int i = t; i < NBUK; i += 256) off[i] = mat[i * MATP + blk];
  __syncthreads();
  const int e0 = blk * EPB;
  const int e1 = min(e0 + EPB, NE);
  for (int e = e0 + t; e < e1; e += 256) {
    int d = dst[e];
    int s = src[e];
    int b = d / BNODES;
    int p = atomicAdd(&off[b], 1);
    staging[p] = make_int2(s, d - b * BNODES);
  }
}

__global__ __launch_bounds__(256) void place2_k(const int* __restrict__ row_ptr,
                                                const int2* __restrict__ staging, int* __restrict__ ssorted) {
  __shared__ int cur[BNODES];
  const int b = blockIdx.x;
  const int t = threadIdx.x;
  const int nbase = b * BNODES;
  if (t < BNODES) cur[t] = row_ptr[nbase + t];
  __syncthreads();
  const int lo = row_ptr[nbase];
  const int hi = row_ptr[nbase + BNODES];
  for (int i = lo + t; i < hi; i += 256) {
    int2 v = staging[i];
    int p = atomicAdd(&cur[v.y], 1);
    ssorted[p] = v.x;
  }
}

// ---------- fp32 -> bf16 hi/lo split (layer-0 input only) ----------
__global__ __launch_bounds__(256) void split_k(const float* __restrict__ h,
                                               u16* __restrict__ xh, u16* __restrict__ xl) {
  int i = blockIdx.x * 256 + threadIdx.x;
  float4 v = reinterpret_cast<const float4*>(h)[i];
  ushort4 hv, lv;
  hv.x = f2bf(v.x); lv.x = f2bf(v.x - b2f(hv.x));
  hv.y = f2bf(v.y); lv.y = f2bf(v.y - b2f(hv.y));
  hv.z = f2bf(v.z); lv.z = f2bf(v.z - b2f(hv.z));
  hv.w = f2bf(v.w); lv.w = f2bf(v.w - b2f(hv.w));
  reinterpret_cast<ushort4*>(xh)[i] = hv;
  reinterpret_cast<ushort4*>(xl)[i] = lv;
}

// ---------- weight prep: W[128][J] -> MFMA-fragment-order hi/lo ----------
// layout: wfrag[((t*4+ks)*64 + lane)*8 + j] = W[k][col], col=t*16+(lane&15), k=ks*32+(lane>>4)*8+j
__global__ __launch_bounds__(256) void wprep_k(const float* __restrict__ W, int J, int Jpad,
                                               u16* __restrict__ wh, u16* __restrict__ wl) {
  int idx = blockIdx.x * 256 + threadIdx.x;
  if (idx >= Jpad * 128) return;
  int j = idx & 7;
  int lane = (idx >> 3) & 63;
  int ks = (idx >> 9) & 3;
  int t = idx >> 11;
  int lr = lane & 15, lg = lane >> 4;
  int col = t * 16 + lr;
  int k = ks * 32 + lg * 8 + j;
  float v = (col < J) ? W[k * J + col] : 0.f;
  u16 hv = f2bf(v);
  wh[idx] = hv;
  wl[idx] = f2bf(v - b2f(hv));
}

// ---------- mean aggregation: one wave64 per node, plain bf16 out ----------
__global__ __launch_bounds__(256) void agg_k(const u16* __restrict__ x, const int* __restrict__ row_ptr,
                                             const int* __restrict__ ss, u16* __restrict__ agg) {
  int gid = blockIdx.x * 256 + threadIdx.x;
  int node = gid >> 6;
  int lane = threadIdx.x & 63;
  if (node >= NN) return;
  int s0 = row_ptr[node], s1 = row_ptr[node + 1];
  float ax = 0.f, ay = 0.f;
  int e = s0;
  for (; e + 2 <= s1; e += 2) {
    int sA = ss[e], sB = ss[e + 1];
    unsigned a = *reinterpret_cast<const unsigned*>(x + (size_t)sA * 128 + lane * 2);
    unsigned b = *reinterpret_cast<const unsigned*>(x + (size_t)sB * 128 + lane * 2);
    ax += bflo(a) + bflo(b);
    ay += bfhi(a) + bfhi(b);
  }
  if (e < s1) {
    unsigned a = *reinterpret_cast<const unsigned*>(x + (size_t)ss[e] * 128 + lane * 2);
    ax += bflo(a);
    ay += bfhi(a);
  }
  float sc = (s1 > s0) ? 1.0f / (float)(s1 - s0) : 0.0f;
  *reinterpret_cast<unsigned*>(agg + (size_t)node * 128 + lane * 2) =
      (unsigned)f2bf(ax * sc) | ((unsigned)f2bf(ay * sc) << 16);
}

// ---------- register-blocked GEMM stream: 64 rows/wave, B frags reused 4x ----------
// acc[NT][4] += A(@+A2)@Bh + A@Bl over K=128 (fragment-order B)
template <int NT, int XS>
__device__ __forceinline__ void gstream(const u16* __restrict__ A, const u16* __restrict__ A2,
                                        const u16* __restrict__ Bh, const u16* __restrict__ Bl,
                                        int r0w, int lane, int lr, int lg, f32x4 (&acc)[NT][4]) {
#pragma unroll
  for (int ks = 0; ks < 4; ++ks) {
    const int ko = ks * 32 + lg * 8;
    bf16x8 ah[4], al[4];
#pragma unroll
    for (int rg = 0; rg < 4; ++rg) {
      int row = r0w + rg * 16 + lr;
      if (row >= NN) row = NN - 1;
      ah[rg] = *reinterpret_cast<const bf16x8*>(A + (size_t)row * 128 + ko);
      if (XS) al[rg] = *reinterpret_cast<const bf16x8*>(A2 + (size_t)row * 128 + ko);
    }
#pragma unroll
    for (int t = 0; t < NT; ++t) {
      const size_t bo = (size_t)((t * 4 + ks) * 64 + lane) * 8;
      bf16x8 bh = *reinterpret_cast<const bf16x8*>(Bh + bo);
      bf16x8 bl = *reinterpret_cast<const bf16x8*>(Bl + bo);
#pragma unroll
      for (int rg = 0; rg < 4; ++rg) {
        acc[t][rg] = MFMA16(ah[rg], bh, acc[t][rg]);
        if (XS) acc[t][rg] = MFMA16(al[rg], bh, acc[t][rg]);
        acc[t][rg] = MFMA16(ah[rg], bl, acc[t][rg]);
      }
    }
  }
}

// ---------- fused SAGE layer: GEMM + bias + LN + ReLU; 64 rows/wave, 256 rows/block ----------
template <int XSPLIT>
__global__ __launch_bounds__(256, 2) void gemm_ln_k(
    const u16* __restrict__ xh, const u16* __restrict__ xl, const u16* __restrict__ ag,
    const u16* __restrict__ wsh, const u16* __restrict__ wsl,
    const u16* __restrict__ wnh, const u16* __restrict__ wnl,
    const float* __restrict__ bias, const float* __restrict__ gamma, const float* __restrict__ beta,
    u16* __restrict__ yh) {
  const int lane = threadIdx.x & 63;
  const int wv = threadIdx.x >> 6;
  const int r0w = blockIdx.x * 256 + wv * 64;
  if (r0w >= NN) return;
  const int lr = lane & 15, lg = lane >> 4;

  f32x4 acc[8][4];
#pragma unroll
  for (int t = 0; t < 8; ++t)
#pragma unroll
    for (int rg = 0; rg < 4; ++rg) acc[t][rg] = f32x4{0.f, 0.f, 0.f, 0.f};

  gstream<8, XSPLIT>(xh, xl, wsh, wsl, r0w, lane, lr, lg, acc);
  gstream<8, 0>(ag, nullptr, wnh, wnl, r0w, lane, lr, lg, acc);

  float bcol[8], gcol[8], ecol[8];
#pragma unroll
  for (int t = 0; t < 8; ++t) {
    int c = t * 16 + lr;
    bcol[t] = bias[c];
    gcol[t] = gamma[c];
    ecol[t] = beta[c];
  }

#pragma unroll
  for (int rg = 0; rg < 4; ++rg) {
    float v[8][4];
#pragma unroll
    for (int t = 0; t < 8; ++t)
#pragma unroll
      for (int e = 0; e < 4; ++e) v[t][e] = acc[t][rg][e] + bcol[t];
    float mu[4], inv[4];
#pragma unroll
    for (int e = 0; e < 4; ++e) {
      float s = 0.f;
#pragma unroll
      for (int t = 0; t < 8; ++t) s += v[t][e];
      s += __shfl_xor(s, 1, 64);
      s += __shfl_xor(s, 2, 64);
      s += __shfl_xor(s, 4, 64);
      s += __shfl_xor(s, 8, 64);
      mu[e] = s * 0.0078125f;
    }
#pragma unroll
    for (int e = 0; e < 4; ++e) {
      float q = 0.f;
#pragma unroll
      for (int t = 0; t < 8; ++t) {
        float d = v[t][e] - mu[e];
        q += d * d;
      }
      q += __shfl_xor(q, 1, 64);
      q += __shfl_xor(q, 2, 64);
      q += __shfl_xor(q, 4, 64);
      q += __shfl_xor(q, 8, 64);
      inv[e] = rsqrtf(q * 0.0078125f + EPSV);
    }
#pragma unroll
    for (int t = 0; t < 8; ++t)
#pragma unroll
      for (int e = 0; e < 4; ++e) {
        int row = r0w + rg * 16 + lg * 4 + e;
        if (row < NN) {
          float o = fmaxf((v[t][e] - mu[e]) * inv[e] * gcol[t] + ecol[t], 0.f);
          yh[(size_t)row * 128 + t * 16 + lr] = f2bf(o);
        }
      }
  }
}

// ---------- final layer: [N,128]@[128,47] x2 + bias -> fp32; 64 rows/wave ----------
__global__ __launch_bounds__(256, 2) void gemm_out_k(
    const u16* __restrict__ x, const u16* __restrict__ ag,
    const u16* __restrict__ wsh, const u16* __restrict__ wsl,
    const u16* __restrict__ wnh, const u16* __restrict__ wnl,
    const float* __restrict__ bias, float* __restrict__ out) {
  const int lane = threadIdx.x & 63;
  const int wv = threadIdx.x >> 6;
  const int r0w = blockIdx.x * 256 + wv * 64;
  if (r0w >= NN) return;
  const int lr = lane & 15, lg = lane >> 4;

  f32x4 acc[3][4];
#pragma unroll
  for (int t = 0; t < 3; ++t)
#pragma unroll
    for (int rg = 0; rg < 4; ++rg) acc[t][rg] = f32x4{0.f, 0.f, 0.f, 0.f};

  gstream<3, 0>(x, nullptr, wsh, wsl, r0w, lane, lr, lg, acc);
  gstream<3, 0>(ag, nullptr, wnh, wnl, r0w, lane, lr, lg, acc);

  float bcol[3];
#pragma unroll
  for (int t = 0; t < 3; ++t) {
    int c = t * 16 + lr;
    bcol[t] = (c < 47) ? bias[c] : 0.f;
  }
#pragma unroll
  for (int rg = 0; rg < 4; ++rg)
#pragma unroll
    for (int t = 0; t < 3; ++t) {
      int col = t * 16 + lr;
      if (col < 47) {
#pragma unroll
        for (int e = 0; e < 4; ++e) {
          int row = r0w + rg * 16 + lg * 4 + e;
          if (row < NN) out[(size_t)row * 47 + col] = acc[t][rg][e] + bcol[t];
        }
      }
    }
}

extern "C" void kernel_launch(void* const* d_in, const int* in_sizes, int n_in,
                              void* d_out, int out_size, void* d_ws, size_t ws_size,
                              hipStream_t stream) {
  const float* h = (const float*)d_in[0];
  const int* src = (const int*)d_in[1];
  const int* dst = (const int*)d_in[2];
  const float* Ws0 = (const float*)d_in[3];
  const float* Wn0 = (const float*)d_in[4];
  const float* b0 = (const float*)d_in[5];
  const float* g0 = (const float*)d_in[6];
  const float* be0 = (const float*)d_in[7];
  const float* Ws1 = (const float*)d_in[8];
  const float* Wn1 = (const float*)d_in[9];
  const float* b1 = (const float*)d_in[10];
  const float* g1 = (const float*)d_in[11];
  const float* be1 = (const float*)d_in[12];
  const float* Ws2 = (const float*)d_in[13];
  const float* Wn2 = (const float*)d_in[14];
  const float* b2 = (const float*)d_in[15];
  float* out = (float*)d_out;

  // workspace layout (all 16B aligned)
  u16* x_hi = (u16*)d_ws;                       // N*128
  u16* x_lo = x_hi + (size_t)NN * 128;          // N*128 (layer-0 input lo)
  u16* aggb = x_lo + (size_t)NN * 128;          // N*128 (plain bf16 agg)
  u16* spare = aggb + (size_t)NN * 128;         // N*128 spare (CSR temps)
  int* row_ptr = (int*)(spare + (size_t)NN * 128);   // N+1 (+pad)
  int* ssorted = row_ptr + (NN + 4);            // E
  int* partial = ssorted + NE;                  // SNB (+pad)
  u16* wbuf = (u16*)(partial + 128);
  u16 *w0sh = wbuf, *w0sl = wbuf + 16384, *w0nh = wbuf + 32768, *w0nl = wbuf + 49152;
  u16 *w1sh = wbuf + 65536, *w1sl = wbuf + 81920, *w1nh = wbuf + 98304, *w1nl = wbuf + 114688;
  u16 *w2sh = wbuf + 131072, *w2sl = wbuf + 137216, *w2nh = wbuf + 143360, *w2nl = wbuf + 149504;
  // CSR temps live in aggb/spare before first agg_k write:
  int* cnt = (int*)aggb;                   // N counts (hist)
  int* mat = cnt + NN;                     // NBUK*MATP offsets (800 KB)
  int2* staging = (int2*)spare;            // E packed (src, dst_local) (12.8 MB)

  // CSR build: hist -> hierarchical scan -> atomic-free multisplit -> bucket scatter
  hipMemsetAsync(cnt, 0, NN * sizeof(int), stream);
  hist_k<<<(NE + 255) / 256, 256, 0, stream>>>(dst, cnt);
  scan1_k<<<SNB, 256, 0, stream>>>(cnt, partial);
  scan2_k<<<1, 128, 0, stream>>>(partial);
  scan3_k<<<SNB, 256, 0, stream>>>(cnt, partial, row_ptr);
  mcount_k<<<NMB, 256, 0, stream>>>(dst, mat);
  mscan_k<<<NBUK, 256, 0, stream>>>(mat, row_ptr);
  mscatter_k<<<NMB, 256, 0, stream>>>(src, dst, mat, staging);
  place2_k<<<NBUK, 256, 0, stream>>>(row_ptr, staging, ssorted);

  // feature split + weight prep (fragment-order)
  split_k<<<(NN * 128 / 4 + 255) / 256, 256, 0, stream>>>(h, x_hi, x_lo);
  wprep_k<<<64, 256, 0, stream>>>(Ws0, 128, 128, w0sh, w0sl);
  wprep_k<<<64, 256, 0, stream>>>(Wn0, 128, 128, w0nh, w0nl);
  wprep_k<<<64, 256, 0, stream>>>(Ws1, 128, 128, w1sh, w1sl);
  wprep_k<<<64, 256, 0, stream>>>(Wn1, 128, 128, w1nh, w1nl);
  wprep_k<<<24, 256, 0, stream>>>(Ws2, 47, 48, w2sh, w2sl);
  wprep_k<<<24, 256, 0, stream>>>(Wn2, 47, 48, w2nh, w2nl);

  const int AGG_GRID = (NN * 64 + 255) / 256;
  const int GEMM_GRID = (NN + 255) / 256;

  // layer 0 (x split hi+lo)
  agg_k<<<AGG_GRID, 256, 0, stream>>>(x_hi, row_ptr, ssorted, aggb);
  gemm_ln_k<1><<<GEMM_GRID, 256, 0, stream>>>(x_hi, x_lo, aggb,
                                              w0sh, w0sl, w0nh, w0nl, b0, g0, be0, x_hi);
  // layer 1 (plain bf16 activations, in-place)
  agg_k<<<AGG_GRID, 256, 0, stream>>>(x_hi, row_ptr, ssorted, aggb);
  gemm_ln_k<0><<<GEMM_GRID, 256, 0, stream>>>(x_hi, nullptr, aggb,
                                              w1sh, w1sl, w1nh, w1nl, b1, g1, be1, x_hi);
  // layer 2
  agg_k<<<AGG_GRID, 256, 0, stream>>>(x_hi, row_ptr, ssorted, aggb);
  gemm_out_k<<<GEMM_GRID, 256, 0, stream>>>(x_hi, aggb,
                                            w2sh, w2sl, w2nh, w2nl, b2, out);
}

// Round 9
// 428.764 us; speedup vs baseline: 1.6200x; 1.2262x over previous
//
#include <hip/hip_runtime.h>

#define NN 100000
#define NE 1600000
#define EPSV 1e-5f
#define SCHUNK 1024
#define SNB ((NN + SCHUNK - 1) / SCHUNK)  // 98
#define BNODES 200
#define NBUK (NN / BNODES)  // 500
#define EPB 4096
#define NMB ((NE + EPB - 1) / EPB)  // 391
#define MATP 400

typedef unsigned short u16;
typedef __attribute__((ext_vector_type(8))) short bf16x8;
typedef __attribute__((ext_vector_type(4))) float f32x4;

#define MFMA16(a, b, c) __builtin_amdgcn_mfma_f32_16x16x32_bf16(a, b, c, 0, 0, 0)

__device__ __forceinline__ u16 f2bf(float f) {
  unsigned u = __float_as_uint(f);
  unsigned r = u + 0x7fffu + ((u >> 16) & 1u);
  return (u16)(r >> 16);
}
__device__ __forceinline__ float b2f(u16 h) { return __uint_as_float(((unsigned)h) << 16); }
__device__ __forceinline__ float bflo(unsigned u) { return __uint_as_float(u << 16); }
__device__ __forceinline__ float bfhi(unsigned u) { return __uint_as_float(u & 0xffff0000u); }

// ---------- CSR build ----------
__global__ __launch_bounds__(256) void hist_k(const int* __restrict__ dst, int* __restrict__ cnt) {
  int e = blockIdx.x * 256 + threadIdx.x;
  if (e < NE) atomicAdd(&cnt[dst[e]], 1);
}

__global__ __launch_bounds__(256) void scan1_k(const int* __restrict__ cnt, int* __restrict__ partial) {
  __shared__ int ws[4];
  const int t = threadIdx.x;
  const int base = blockIdx.x * SCHUNK;
  int s = 0;
  for (int i = t; i < SCHUNK; i += 256) {
    int idx = base + i;
    s += (idx < NN) ? cnt[idx] : 0;
  }
#pragma unroll
  for (int m = 1; m < 64; m <<= 1) s += __shfl_xor(s, m, 64);
  if ((t & 63) == 0) ws[t >> 6] = s;
  __syncthreads();
  if (t == 0) partial[blockIdx.x] = ws[0] + ws[1] + ws[2] + ws[3];
}

__global__ __launch_bounds__(128) void scan2_k(int* __restrict__ partial) {
  __shared__ int sm[128];
  const int t = threadIdx.x;
  int v = (t < SNB) ? partial[t] : 0;
  sm[t] = v;
  __syncthreads();
  for (int off = 1; off < 128; off <<= 1) {
    int u = (t >= off) ? sm[t - off] : 0;
    __syncthreads();
    sm[t] += u;
    __syncthreads();
  }
  if (t < SNB) partial[t] = sm[t] - v;
}

__global__ __launch_bounds__(256) void scan3_k(const int* __restrict__ cnt, const int* __restrict__ partial,
                                               int* __restrict__ row_ptr) {
  __shared__ int sm[256];
  const int t = threadIdx.x;
  const int base = blockIdx.x * SCHUNK + t * 4;
  int c[4];
  int s = 0;
#pragma unroll
  for (int i = 0; i < 4; ++i) {
    int idx = base + i;
    c[i] = (idx < NN) ? cnt[idx] : 0;
    s += c[i];
  }
  sm[t] = s;
  __syncthreads();
  for (int off = 1; off < 256; off <<= 1) {
    int u = (t >= off) ? sm[t - off] : 0;
    __syncthreads();
    sm[t] += u;
    __syncthreads();
  }
  int run = partial[blockIdx.x] + sm[t] - s;
#pragma unroll
  for (int i = 0; i < 4; ++i) {
    int idx = base + i;
    if (idx < NN) {
      row_ptr[idx] = run;
      run += c[i];
    }
  }
  if (blockIdx.x == 0 && t == 0) row_ptr[NN] = NE;
}

// ---------- block multisplit into 500 buckets (no global atomics) ----------
__global__ __launch_bounds__(256) void mcount_k(const int* __restrict__ dst, int* __restrict__ mat) {
  __shared__ int cnt[NBUK];
  const int t = threadIdx.x;
  const int blk = blockIdx.x;
  for (int i = t; i < NBUK; i += 256) cnt[i] = 0;
  __syncthreads();
  const int e0 = blk * EPB;
  const int e1 = min(e0 + EPB, NE);
  for (int e = e0 + t; e < e1; e += 256) atomicAdd(&cnt[dst[e] / BNODES], 1);
  __syncthreads();
  for (int i = t; i < NBUK; i += 256) mat[i * MATP + blk] = cnt[i];
}

__global__ __launch_bounds__(256) void mscan_k(int* __restrict__ mat, const int* __restrict__ row_ptr) {
  __shared__ int sm[512];
  const int b = blockIdx.x;
  const int t = threadIdx.x;
  sm[t] = (t < NMB) ? mat[b * MATP + t] : 0;
  sm[t + 256] = (t + 256 < NMB) ? mat[b * MATP + t + 256] : 0;
  __syncthreads();
  for (int off = 1; off < 512; off <<= 1) {
    int a0 = (t >= off) ? sm[t - off] : 0;
    int a1 = (t + 256 >= off) ? sm[t + 256 - off] : 0;
    __syncthreads();
    sm[t] += a0;
    sm[t + 256] += a1;
    __syncthreads();
  }
  const int base = row_ptr[b * BNODES];
  if (t < NMB) mat[b * MATP + t] = base + ((t == 0) ? 0 : sm[t - 1]);
  if (t + 256 < NMB) mat[b * MATP + t + 256] = base + sm[t + 255];
}

__global__ __launch_bounds__(256) void mscatter_k(const int* __restrict__ src, const int* __restrict__ dst,
                                                  const int* __restrict__ mat, int2* __restrict__ staging) {
  __shared__ int off[NBUK];
  const int t = threadIdx.x;
  const int blk = blockIdx.x;
  for (int i = t; i < NBUK; i += 256) off[i] = mat[i * MATP + blk];
  __syncthreads();
  const int e0 = blk * EPB;
  const int e1 = min(e0 + EPB, NE);
  for (int e = e0 + t; e < e1; e += 256) {
    int d = dst[e];
    int s = src[e];
    int b = d / BNODES;
    int p = atomicAdd(&off[b], 1);
    staging[p] = make_int2(s, d - b * BNODES);
  }
}

__global__ __launch_bounds__(256) void place2_k(const int* __restrict__ row_ptr,
                                                const int2* __restrict__ staging, int* __restrict__ ssorted) {
  __shared__ int cur[BNODES];
  const int b = blockIdx.x;
  const int t = threadIdx.x;
  const int nbase = b * BNODES;
  if (t < BNODES) cur[t] = row_ptr[nbase + t];
  __syncthreads();
  const int lo = row_ptr[nbase];
  const int hi = row_ptr[nbase + BNODES];
  for (int i = lo + t; i < hi; i += 256) {
    int2 v = staging[i];
    int p = atomicAdd(&cur[v.y], 1);
    ssorted[p] = v.x;
  }
}

// ---------- fp32 -> bf16 hi/lo split (layer-0 input only) ----------
__global__ __launch_bounds__(256) void split_k(const float* __restrict__ h,
                                               u16* __restrict__ xh, u16* __restrict__ xl) {
  int i = blockIdx.x * 256 + threadIdx.x;
  float4 v = reinterpret_cast<const float4*>(h)[i];
  ushort4 hv, lv;
  hv.x = f2bf(v.x); lv.x = f2bf(v.x - b2f(hv.x));
  hv.y = f2bf(v.y); lv.y = f2bf(v.y - b2f(hv.y));
  hv.z = f2bf(v.z); lv.z = f2bf(v.z - b2f(hv.z));
  hv.w = f2bf(v.w); lv.w = f2bf(v.w - b2f(hv.w));
  reinterpret_cast<ushort4*>(xh)[i] = hv;
  reinterpret_cast<ushort4*>(xl)[i] = lv;
}

// ---------- weight prep: W[128][J] -> MFMA-fragment-order hi/lo ----------
// layout: wfrag[((t*4+ks)*64 + lane)*8 + j] = W[k][col], col=t*16+(lane&15), k=ks*32+(lane>>4)*8+j
__global__ __launch_bounds__(256) void wprep_k(const float* __restrict__ W, int J, int Jpad,
                                               u16* __restrict__ wh, u16* __restrict__ wl) {
  int idx = blockIdx.x * 256 + threadIdx.x;
  if (idx >= Jpad * 128) return;
  int j = idx & 7;
  int lane = (idx >> 3) & 63;
  int ks = (idx >> 9) & 3;
  int t = idx >> 11;
  int lr = lane & 15, lg = lane >> 4;
  int col = t * 16 + lr;
  int k = ks * 32 + lg * 8 + j;
  float v = (col < J) ? W[k * J + col] : 0.f;
  u16 hv = f2bf(v);
  wh[idx] = hv;
  wl[idx] = f2bf(v - b2f(hv));
}

// ---------- mean aggregation: one wave64 per node, 8 row-loads in flight ----------
__global__ __launch_bounds__(256) void agg_k(const u16* __restrict__ x, const int* __restrict__ row_ptr,
                                             const int* __restrict__ ss, u16* __restrict__ agg) {
  int gid = blockIdx.x * 256 + threadIdx.x;
  int node = gid >> 6;
  int lane = threadIdx.x & 63;
  if (node >= NN) return;
  int s0 = row_ptr[node], s1 = row_ptr[node + 1];
  float ax = 0.f, ay = 0.f;
  int e = s0;
  for (; e + 8 <= s1; e += 8) {
    int si[8];
#pragma unroll
    for (int i = 0; i < 8; ++i) si[i] = ss[e + i];
    unsigned r[8];
#pragma unroll
    for (int i = 0; i < 8; ++i)
      r[i] = *reinterpret_cast<const unsigned*>(x + (size_t)si[i] * 128 + lane * 2);
#pragma unroll
    for (int i = 0; i < 8; ++i) {
      ax += bflo(r[i]);
      ay += bfhi(r[i]);
    }
  }
  if (e + 4 <= s1) {
    int si[4];
#pragma unroll
    for (int i = 0; i < 4; ++i) si[i] = ss[e + i];
    unsigned r[4];
#pragma unroll
    for (int i = 0; i < 4; ++i)
      r[i] = *reinterpret_cast<const unsigned*>(x + (size_t)si[i] * 128 + lane * 2);
#pragma unroll
    for (int i = 0; i < 4; ++i) {
      ax += bflo(r[i]);
      ay += bfhi(r[i]);
    }
    e += 4;
  }
  for (; e < s1; ++e) {
    unsigned a = *reinterpret_cast<const unsigned*>(x + (size_t)ss[e] * 128 + lane * 2);
    ax += bflo(a);
    ay += bfhi(a);
  }
  float sc = (s1 > s0) ? 1.0f / (float)(s1 - s0) : 0.0f;
  *reinterpret_cast<unsigned*>(agg + (size_t)node * 128 + lane * 2) =
      (unsigned)f2bf(ax * sc) | ((unsigned)f2bf(ay * sc) << 16);
}

// ---------- register-blocked GEMM stream: 64 rows/wave, B frags reused 4x ----------
template <int NT, int XS>
__device__ __forceinline__ void gstream(const u16* __restrict__ A, const u16* __restrict__ A2,
                                        const u16* __restrict__ Bh, const u16* __restrict__ Bl,
                                        int r0w, int lane, int lr, int lg, f32x4 (&acc)[NT][4]) {
#pragma unroll
  for (int ks = 0; ks < 4; ++ks) {
    const int ko = ks * 32 + lg * 8;
    bf16x8 ah[4], al[4];
#pragma unroll
    for (int rg = 0; rg < 4; ++rg) {
      int row = r0w + rg * 16 + lr;
      if (row >= NN) row = NN - 1;
      ah[rg] = *reinterpret_cast<const bf16x8*>(A + (size_t)row * 128 + ko);
      if (XS) al[rg] = *reinterpret_cast<const bf16x8*>(A2 + (size_t)row * 128 + ko);
    }
#pragma unroll
    for (int t = 0; t < NT; ++t) {
      const size_t bo = (size_t)((t * 4 + ks) * 64 + lane) * 8;
      bf16x8 bh = *reinterpret_cast<const bf16x8*>(Bh + bo);
      bf16x8 bl = *reinterpret_cast<const bf16x8*>(Bl + bo);
#pragma unroll
      for (int rg = 0; rg < 4; ++rg) {
        acc[t][rg] = MFMA16(ah[rg], bh, acc[t][rg]);
        if (XS) acc[t][rg] = MFMA16(al[rg], bh, acc[t][rg]);
        acc[t][rg] = MFMA16(ah[rg], bl, acc[t][rg]);
      }
    }
  }
}

// ---------- fused SAGE layer: GEMM + bias + LN + ReLU; 64 rows/wave, 256 rows/block ----------
template <int XSPLIT>
__global__ __launch_bounds__(256, 2) void gemm_ln_k(
    const u16* __restrict__ xh, const u16* __restrict__ xl, const u16* __restrict__ ag,
    const u16* __restrict__ wsh, const u16* __restrict__ wsl,
    const u16* __restrict__ wnh, const u16* __restrict__ wnl,
    const float* __restrict__ bias, const float* __restrict__ gamma, const float* __restrict__ beta,
    u16* __restrict__ yh) {
  const int lane = threadIdx.x & 63;
  const int wv = threadIdx.x >> 6;
  const int r0w = blockIdx.x * 256 + wv * 64;
  if (r0w >= NN) return;
  const int lr = lane & 15, lg = lane >> 4;

  f32x4 acc[8][4];
#pragma unroll
  for (int t = 0; t < 8; ++t)
#pragma unroll
    for (int rg = 0; rg < 4; ++rg) acc[t][rg] = f32x4{0.f, 0.f, 0.f, 0.f};

  gstream<8, XSPLIT>(xh, xl, wsh, wsl, r0w, lane, lr, lg, acc);
  gstream<8, 0>(ag, nullptr, wnh, wnl, r0w, lane, lr, lg, acc);

  float bcol[8], gcol[8], ecol[8];
#pragma unroll
  for (int t = 0; t < 8; ++t) {
    int c = t * 16 + lr;
    bcol[t] = bias[c];
    gcol[t] = gamma[c];
    ecol[t] = beta[c];
  }

#pragma unroll
  for (int rg = 0; rg < 4; ++rg) {
    float v[8][4];
#pragma unroll
    for (int t = 0; t < 8; ++t)
#pragma unroll
      for (int e = 0; e < 4; ++e) v[t][e] = acc[t][rg][e] + bcol[t];
    float mu[4], inv[4];
#pragma unroll
    for (int e = 0; e < 4; ++e) {
      float s = 0.f;
#pragma unroll
      for (int t = 0; t < 8; ++t) s += v[t][e];
      s += __shfl_xor(s, 1, 64);
      s += __shfl_xor(s, 2, 64);
      s += __shfl_xor(s, 4, 64);
      s += __shfl_xor(s, 8, 64);
      mu[e] = s * 0.0078125f;
    }
#pragma unroll
    for (int e = 0; e < 4; ++e) {
      float q = 0.f;
#pragma unroll
      for (int t = 0; t < 8; ++t) {
        float d = v[t][e] - mu[e];
        q += d * d;
      }
      q += __shfl_xor(q, 1, 64);
      q += __shfl_xor(q, 2, 64);
      q += __shfl_xor(q, 4, 64);
      q += __shfl_xor(q, 8, 64);
      inv[e] = rsqrtf(q * 0.0078125f + EPSV);
    }
#pragma unroll
    for (int t = 0; t < 8; ++t)
#pragma unroll
      for (int e = 0; e < 4; ++e) {
        int row = r0w + rg * 16 + lg * 4 + e;
        if (row < NN) {
          float o = fmaxf((v[t][e] - mu[e]) * inv[e] * gcol[t] + ecol[t], 0.f);
          yh[(size_t)row * 128 + t * 16 + lr] = f2bf(o);
        }
      }
  }
}

// ---------- final layer: [N,128]@[128,47] x2 + bias -> fp32; 64 rows/wave ----------
__global__ __launch_bounds__(256, 2) void gemm_out_k(
    const u16* __restrict__ x, const u16* __restrict__ ag,
    const u16* __restrict__ wsh, const u16* __restrict__ wsl,
    const u16* __restrict__ wnh, const u16* __restrict__ wnl,
    const float* __restrict__ bias, float* __restrict__ out) {
  const int lane = threadIdx.x & 63;
  const int wv = threadIdx.x >> 6;
  const int r0w = blockIdx.x * 256 + wv * 64;
  if (r0w >= NN) return;
  const int lr = lane & 15, lg = lane >> 4;

  f32x4 acc[3][4];
#pragma unroll
  for (int t = 0; t < 3; ++t)
#pragma unroll
    for (int rg = 0; rg < 4; ++rg) acc[t][rg] = f32x4{0.f, 0.f, 0.f, 0.f};

  gstream<3, 0>(x, nullptr, wsh, wsl, r0w, lane, lr, lg, acc);
  gstream<3, 0>(ag, nullptr, wnh, wnl, r0w, lane, lr, lg, acc);

  float bcol[3];
#pragma unroll
  for (int t = 0; t < 3; ++t) {
    int c = t * 16 + lr;
    bcol[t] = (c < 47) ? bias[c] : 0.f;
  }
#pragma unroll
  for (int rg = 0; rg < 4; ++rg)
#pragma unroll
    for (int t = 0; t < 3; ++t) {
      int col = t * 16 + lr;
      if (col < 47) {
#pragma unroll
        for (int e = 0; e < 4; ++e) {
          int row = r0w + rg * 16 + lg * 4 + e;
          if (row < NN) out[(size_t)row * 47 + col] = acc[t][rg][e] + bcol[t];
        }
      }
    }
}

extern "C" void kernel_launch(void* const* d_in, const int* in_sizes, int n_in,
                              void* d_out, int out_size, void* d_ws, size_t ws_size,
                              hipStream_t stream) {
  const float* h = (const float*)d_in[0];
  const int* src = (const int*)d_in[1];
  const int* dst = (const int*)d_in[2];
  const float* Ws0 = (const float*)d_in[3];
  const float* Wn0 = (const float*)d_in[4];
  const float* b0 = (const float*)d_in[5];
  const float* g0 = (const float*)d_in[6];
  const float* be0 = (const float*)d_in[7];
  const float* Ws1 = (const float*)d_in[8];
  const float* Wn1 = (const float*)d_in[9];
  const float* b1 = (const float*)d_in[10];
  const float* g1 = (const float*)d_in[11];
  const float* be1 = (const float*)d_in[12];
  const float* Ws2 = (const float*)d_in[13];
  const float* Wn2 = (const float*)d_in[14];
  const float* b2 = (const float*)d_in[15];
  float* out = (float*)d_out;

  // workspace layout (all 16B aligned)
  u16* x_hi = (u16*)d_ws;                       // N*128
  u16* x_lo = x_hi + (size_t)NN * 128;          // N*128 (layer-0 input lo)
  u16* aggb = x_lo + (size_t)NN * 128;          // N*128 (plain bf16 agg)
  u16* spare = aggb + (size_t)NN * 128;         // N*128 spare (CSR temps)
  int* row_ptr = (int*)(spare + (size_t)NN * 128);   // N+1 (+pad)
  int* ssorted = row_ptr + (NN + 4);            // E
  int* partial = ssorted + NE;                  // SNB (+pad)
  u16* wbuf = (u16*)(partial + 128);
  u16 *w0sh = wbuf, *w0sl = wbuf + 16384, *w0nh = wbuf + 32768, *w0nl = wbuf + 49152;
  u16 *w1sh = wbuf + 65536, *w1sl = wbuf + 81920, *w1nh = wbuf + 98304, *w1nl = wbuf + 114688;
  u16 *w2sh = wbuf + 131072, *w2sl = wbuf + 137216, *w2nh = wbuf + 143360, *w2nl = wbuf + 149504;
  // CSR temps live in aggb/spare before first agg_k write:
  int* cnt = (int*)aggb;                   // N counts (hist)
  int* mat = cnt + NN;                     // NBUK*MATP offsets (800 KB)
  int2* staging = (int2*)spare;            // E packed (src, dst_local) (12.8 MB)

  // CSR build: hist -> hierarchical scan -> atomic-free multisplit -> bucket scatter
  hipMemsetAsync(cnt, 0, NN * sizeof(int), stream);
  hist_k<<<(NE + 255) / 256, 256, 0, stream>>>(dst, cnt);
  scan1_k<<<SNB, 256, 0, stream>>>(cnt, partial);
  scan2_k<<<1, 128, 0, stream>>>(partial);
  scan3_k<<<SNB, 256, 0, stream>>>(cnt, partial, row_ptr);
  mcount_k<<<NMB, 256, 0, stream>>>(dst, mat);
  mscan_k<<<NBUK, 256, 0, stream>>>(mat, row_ptr);
  mscatter_k<<<NMB, 256, 0, stream>>>(src, dst, mat, staging);
  place2_k<<<NBUK, 256, 0, stream>>>(row_ptr, staging, ssorted);

  // feature split + weight prep (fragment-order)
  split_k<<<(NN * 128 / 4 + 255) / 256, 256, 0, stream>>>(h, x_hi, x_lo);
  wprep_k<<<64, 256, 0, stream>>>(Ws0, 128, 128, w0sh, w0sl);
  wprep_k<<<64, 256, 0, stream>>>(Wn0, 128, 128, w0nh, w0nl);
  wprep_k<<<64, 256, 0, stream>>>(Ws1, 128, 128, w1sh, w1sl);
  wprep_k<<<64, 256, 0, stream>>>(Wn1, 128, 128, w1nh, w1nl);
  wprep_k<<<24, 256, 0, stream>>>(Ws2, 47, 48, w2sh, w2sl);
  wprep_k<<<24, 256, 0, stream>>>(Wn2, 47, 48, w2nh, w2nl);

  const int AGG_GRID = (NN * 64 + 255) / 256;
  const int GEMM_GRID = (NN + 255) / 256;

  // layer 0 (x split hi+lo)
  agg_k<<<AGG_GRID, 256, 0, stream>>>(x_hi, row_ptr, ssorted, aggb);
  gemm_ln_k<1><<<GEMM_GRID, 256, 0, stream>>>(x_hi, x_lo, aggb,
                                              w0sh, w0sl, w0nh, w0nl, b0, g0, be0, x_hi);
  // layer 1 (plain bf16 activations, in-place)
  agg_k<<<AGG_GRID, 256, 0, stream>>>(x_hi, row_ptr, ssorted, aggb);
  gemm_ln_k<0><<<GEMM_GRID, 256, 0, stream>>>(x_hi, nullptr, aggb,
                                              w1sh, w1sl, w1nh, w1nl, b1, g1, be1, x_hi);
  // layer 2
  agg_k<<<AGG_GRID, 256, 0, stream>>>(x_hi, row_ptr, ssorted, aggb);
  gemm_out_k<<<GEMM_GRID, 256, 0, stream>>>(x_hi, aggb,
                                            w2sh, w2sl, w2nh, w2nl, b2, out);
}